// Round 3
// baseline (332.594 us; speedup 1.0000x reference)
//
#include <hip/hip_runtime.h>

#define LL 64
#define DD 1024
#define HH 512
#define SS 50000
#define VV 40000
#define KD 32
#define MM 128  // B*L

typedef __bf16 bf16_t;
typedef __bf16 bf16x8 __attribute__((ext_vector_type(8)));
typedef __bf16 bf16x4 __attribute__((ext_vector_type(4)));
typedef __bf16 bf16x2 __attribute__((ext_vector_type(2)));
typedef float f32x4 __attribute__((ext_vector_type(4)));
typedef float f32x2 __attribute__((ext_vector_type(2)));

__device__ __forceinline__ void async_ld16(const void* g, void* l) {
    __builtin_amdgcn_global_load_lds(
        (const __attribute__((address_space(1))) void*)g,
        (__attribute__((address_space(3))) void*)l, 16, 0, 0);
}

// counted vmcnt wait (immediate), memory clobber so no load/ds op crosses it
#define WAITV(N) asm volatile("s_waitcnt vmcnt(" #N ")" ::: "memory")

// ---------------- Kernel 1: BatchNorm over (B, D) per l; write xn bf16 [128][1024]
__global__ __launch_bounds__(256) void k_bn(const float* __restrict__ x,
        const float* __restrict__ gamma, const float* __restrict__ beta,
        bf16_t* __restrict__ xn) {
    int l = blockIdx.x;        // 0..63
    int t = threadIdx.x;       // 0..255
    int b = t >> 7;            // 0..1
    int d0 = (t & 127) << 3;   // 8 elems/thread
    const float* xp = x + (size_t)(b * LL + l) * DD + d0;
    float4 v0 = *(const float4*)xp;
    float4 v1 = *(const float4*)(xp + 4);
    float s  = v0.x + v0.y + v0.z + v0.w + v1.x + v1.y + v1.z + v1.w;
    float ss = v0.x*v0.x + v0.y*v0.y + v0.z*v0.z + v0.w*v0.w
             + v1.x*v1.x + v1.y*v1.y + v1.z*v1.z + v1.w*v1.w;
    #pragma unroll
    for (int off = 32; off > 0; off >>= 1) {
        s  += __shfl_xor(s, off);
        ss += __shfl_xor(ss, off);
    }
    __shared__ float red[8];
    int wv = t >> 6, ln = t & 63;
    if (ln == 0) { red[wv] = s; red[4 + wv] = ss; }
    __syncthreads();
    float tot  = red[0] + red[1] + red[2] + red[3];
    float tots = red[4] + red[5] + red[6] + red[7];
    float mean = tot * (1.0f / 2048.0f);
    float var  = tots * (1.0f / 2048.0f) - mean * mean;
    float rstd = rsqrtf(var + 1e-5f);
    float g   = gamma[l] * rstd;
    float ofs = beta[l] - mean * g;
    bf16x8 o;
    o[0] = (bf16_t)(v0.x * g + ofs);
    o[1] = (bf16_t)(v0.y * g + ofs);
    o[2] = (bf16_t)(v0.z * g + ofs);
    o[3] = (bf16_t)(v0.w * g + ofs);
    o[4] = (bf16_t)(v1.x * g + ofs);
    o[5] = (bf16_t)(v1.y * g + ofs);
    o[6] = (bf16_t)(v1.z * g + ofs);
    o[7] = (bf16_t)(v1.w * g + ofs);
    *(bf16x8*)(xn + (size_t)(b * LL + l) * DD + d0) = o;
}

// ---------------- Kernel 2: h = relu(xn @ W1 + b1), bf16 [128][512]
__global__ __launch_bounds__(64) void k_gemm1(const bf16_t* __restrict__ xn,
        const float* __restrict__ W1, const float* __restrict__ b1,
        bf16_t* __restrict__ h) {
    int lane = threadIdx.x & 63;
    int c = lane & 15, q = lane >> 4;
    int tile = blockIdx.x;           // 256 tiles: 8 m x 32 n
    int tm = tile >> 5, tn = tile & 31;
    int col = tn * 16 + c;
    f32x4 acc = {};
    for (int kk = 0; kk < DD; kk += 32) {
        bf16x8 afr = *(const bf16x8*)(xn + (size_t)(tm * 16 + c) * DD + kk + q * 8);
        bf16x8 bfr;
        #pragma unroll
        for (int j = 0; j < 8; ++j)
            bfr[j] = (bf16_t)W1[(size_t)(kk + q * 8 + j) * HH + col];
        acc = __builtin_amdgcn_mfma_f32_16x16x32_bf16(afr, bfr, acc, 0, 0, 0);
    }
    float bias = b1[col];
    #pragma unroll
    for (int r = 0; r < 4; ++r) {
        int m = tm * 16 + q * 4 + r;   // C/D: col=lane&15, row=q*4+r  [m89]
        float v = acc[r] + bias;
        h[(size_t)m * HH + col] = (bf16_t)(v > 0.f ? v : 0.f);
    }
}

// ---------------- Kernel 3: vT[col][m] = bf16(h @ W_slm + b_slm), transposed
// 2-buffer LDS pipeline (32 KB -> 5 blocks/CU, all 625 blocks resident),
// counted vmcnt(4) distance-1 prefetch, lane-consecutive h chunks (no conflicts).
__global__ __launch_bounds__(256) void k_gemm_v(const bf16_t* __restrict__ h,
        const float* __restrict__ Wslm, const float* __restrict__ bslm,
        bf16_t* __restrict__ vT) {
    __shared__ __align__(16) char smem[2][16384];  // 32 KB: [0..8191]=W, [8192..]=h
    int t = threadIdx.x;
    int wv = t >> 6, lane = t & 63;
    int c = lane & 15, q = lane >> 4;
    int nb = blockIdx.x * 64;          // 40000 = 625*64, exact
    int col = nb + wv * 16 + c;
    int r  = t >> 4, sg = t & 15;      // W staging: rows r and r+16
    const float* gw0 = Wslm + (size_t)r        * VV + nb + sg * 4;
    const float* gw1 = Wslm + (size_t)(r + 16) * VV + nb + sg * 4;
    // h staging: chunk g = ms*64 + q*16 + c  ->  h[ms*16+c][q*8 .. +8] (16B)
    // reader: lane l reads chunk ms*64 + l  (lane-consecutive -> conflict-free)
    int g0i = t, g1i = t + 256;
    const bf16_t* gh0 = h + (size_t)(((g0i >> 6) << 4) + (g0i & 15)) * HH + ((g0i >> 4) & 3) * 8;
    const bf16_t* gh1 = h + (size_t)(((g1i >> 6) << 4) + (g1i & 15)) * HH + ((g1i >> 4) & 3) * 8;

    #define STAGE_V(buf, kk) do { \
        async_ld16(gw0 + (size_t)(kk) * VV, smem[buf] + (size_t)t * 16); \
        async_ld16(gw1 + (size_t)(kk) * VV, smem[buf] + (size_t)(t + 256) * 16); \
        async_ld16(gh0 + (kk), smem[buf] + 8192 + (size_t)t * 16); \
        async_ld16(gh1 + (kk), smem[buf] + 8192 + (size_t)(t + 256) * 16); \
    } while (0)

    STAGE_V(0, 0); STAGE_V(1, 32);     // 8 loads/thread in flight
    f32x4 acc[8] = {};

    auto compute = [&](int cur) {
        const float*  wb = (const float*)smem[cur];
        const bf16_t* hb = (const bf16_t*)(smem[cur] + 8192);
        bf16x8 bfr;
        #pragma unroll
        for (int j = 0; j < 8; ++j)
            bfr[j] = (bf16_t)wb[(q * 8 + j) * 64 + wv * 16 + c];
        #pragma unroll
        for (int ms = 0; ms < 8; ++ms) {
            bf16x8 afr = *(const bf16x8*)(hb + (size_t)(ms * 64 + lane) * 8);
            acc[ms] = __builtin_amdgcn_mfma_f32_16x16x32_bf16(afr, bfr, acc[ms], 0, 0, 0);
        }
    };

    #pragma unroll 1
    for (int step = 0; step < 14; ++step) {
        WAITV(4);                          // stage[step] landed; next stays in flight
        __builtin_amdgcn_s_barrier();
        compute(step & 1);
        __builtin_amdgcn_s_barrier();      // all waves done reading buf
        STAGE_V(step & 1, (step + 2) * 32);
    }
    WAITV(4); __builtin_amdgcn_s_barrier(); compute(0);   // step 14
    WAITV(0); __builtin_amdgcn_s_barrier(); compute(1);   // step 15

    float bias = bslm[col];
    #pragma unroll
    for (int ms = 0; ms < 8; ++ms) {
        bf16x4 o;
        #pragma unroll
        for (int rr = 0; rr < 4; ++rr) o[rr] = (bf16_t)(acc[ms][rr] + bias);
        *(bf16x4*)(vT + (size_t)col * MM + ms * 16 + q * 4) = o;
    }
    #undef STAGE_V
}

// ---------------- Kernel 4: out = h @ W2 + b2 + 0.1 * gather(vT)^T
// Same pipeline as k_gemm_v; the sparse sense->lemma gather is fused as a
// per-block epilogue over the block's own 64 s-columns (L2-bound work that
// overlaps other resident blocks' HBM streaming). slm buffer + kernel gone.
__global__ __launch_bounds__(256) void k_gemm_y(const bf16_t* __restrict__ h,
        const float* __restrict__ W2, const float* __restrict__ b2,
        const bf16_t* __restrict__ vT, const float* __restrict__ slw,
        const int* __restrict__ slidx, float* __restrict__ out) {
    __shared__ __align__(16) char smem[2][16384];  // 32 KB
    int t = threadIdx.x;
    int wv = t >> 6, lane = t & 63;
    int c = lane & 15, q = lane >> 4;
    int nb = blockIdx.x * 64;
    int col = nb + wv * 16 + c;
    int r  = t >> 4, sg = t & 15;
    int sgc = nb + sg * 4;             // first of 4 cols this lane stages
    bool ok = (sgc + 4 <= SS);
    const float* gw0 = ok ? (W2 + (size_t)r        * SS + sgc) : W2;
    const float* gw1 = ok ? (W2 + (size_t)(r + 16) * SS + sgc) : W2;
    int g0i = t, g1i = t + 256;
    const bf16_t* gh0 = h + (size_t)(((g0i >> 6) << 4) + (g0i & 15)) * HH + ((g0i >> 4) & 3) * 8;
    const bf16_t* gh1 = h + (size_t)(((g1i >> 6) << 4) + (g1i & 15)) * HH + ((g1i >> 4) & 3) * 8;

    #define STAGE_Y(buf, kk) do { \
        async_ld16(gw0 + (size_t)(kk) * SS, smem[buf] + (size_t)t * 16); \
        async_ld16(gw1 + (size_t)(kk) * SS, smem[buf] + (size_t)(t + 256) * 16); \
        async_ld16(gh0 + (kk), smem[buf] + 8192 + (size_t)t * 16); \
        async_ld16(gh1 + (kk), smem[buf] + 8192 + (size_t)(t + 256) * 16); \
    } while (0)

    STAGE_Y(0, 0); STAGE_Y(1, 32);
    f32x4 acc[8] = {};

    auto compute = [&](int cur) {
        const float*  wb = (const float*)smem[cur];
        const bf16_t* hb = (const bf16_t*)(smem[cur] + 8192);
        bf16x8 bfr;
        #pragma unroll
        for (int j = 0; j < 8; ++j)
            bfr[j] = (bf16_t)wb[(q * 8 + j) * 64 + wv * 16 + c];
        #pragma unroll
        for (int ms = 0; ms < 8; ++ms) {
            bf16x8 afr = *(const bf16x8*)(hb + (size_t)(ms * 64 + lane) * 8);
            acc[ms] = __builtin_amdgcn_mfma_f32_16x16x32_bf16(afr, bfr, acc[ms], 0, 0, 0);
        }
    };

    #pragma unroll 1
    for (int step = 0; step < 14; ++step) {
        WAITV(4);
        __builtin_amdgcn_s_barrier();
        compute(step & 1);
        __builtin_amdgcn_s_barrier();
        STAGE_Y(step & 1, (step + 2) * 32);
    }
    WAITV(4); __builtin_amdgcn_s_barrier(); compute(0);
    WAITV(0); __builtin_amdgcn_s_barrier(); compute(1);

    // ---- fused gather epilogue: slm[s][m] for this block's 64 s-columns ----
    // LDS (both buffers, 32 KB) becomes slds[64 rows][128 m] fp32, XOR-swizzled.
    float* slds = (float*)&smem[0][0];
    __syncthreads();                   // everyone done reading LDS tiles
    int l31 = lane & 31;
    #pragma unroll 1
    for (int ssi = 0; ssi < 16; ++ssi) {
        int s = nb + wv * 16 + ssi;
        float a0 = 0.f, a1 = 0.f;
        if (s < SS) {
            int   idv = slidx[(size_t)s * KD + l31];
            float wgt = slw[(size_t)s * KD + l31];
            #pragma unroll 1
            for (int half = 0; half < 2; ++half) {
                unsigned u[16];
                #pragma unroll
                for (int k = 0; k < 16; ++k) {
                    int id = __shfl(idv, half * 16 + k);
                    u[k] = *(const unsigned*)(vT + (size_t)id * MM + lane * 2);
                }
                #pragma unroll
                for (int k = 0; k < 16; ++k) {
                    float w = __shfl(wgt, half * 16 + k);
                    a0 += w * __uint_as_float(u[k] << 16);
                    a1 += w * __uint_as_float(u[k] & 0xffff0000u);
                }
            }
        }
        int row = wv * 16 + ssi;
        int widx = (lane * 2) ^ ((ssi & 7) << 2);   // XOR-swizzle, keeps pairs
        f32x2 wr2; wr2[0] = a0; wr2[1] = a1;
        *(f32x2*)&slds[(size_t)row * 128 + widx] = wr2;
    }
    // each wave reads only its own 16 rows -> no barrier needed
    if (col < SS) {
        float bias = b2[col];
        int row = wv * 16 + c;
        #pragma unroll
        for (int ms = 0; ms < 8; ++ms) {
            f32x4 sv = *(const f32x4*)&slds[(size_t)row * 128
                                            + ((ms * 16 + q * 4) ^ ((c & 7) << 2))];
            #pragma unroll
            for (int rr = 0; rr < 4; ++rr) {
                int m = ms * 16 + q * 4 + rr;
                out[(size_t)m * SS + col] = acc[ms][rr] + bias + 0.1f * sv[rr];
            }
        }
    }
    #undef STAGE_Y
}

extern "C" void kernel_launch(void* const* d_in, const int* in_sizes, int n_in,
                              void* d_out, int out_size, void* d_ws, size_t ws_size,
                              hipStream_t stream) {
    const float* x     = (const float*)d_in[0];
    const float* gamma = (const float*)d_in[1];
    const float* beta  = (const float*)d_in[2];
    const float* W1    = (const float*)d_in[3];
    const float* b1    = (const float*)d_in[4];
    const float* W2    = (const float*)d_in[5];
    const float* b2    = (const float*)d_in[6];
    const float* Wslm  = (const float*)d_in[7];
    const float* bslm  = (const float*)d_in[8];
    const float* slw   = (const float*)d_in[9];
    const int*   slidx = (const int*)d_in[10];
    float* out = (float*)d_out;

    char* ws = (char*)d_ws;
    bf16_t* xn  = (bf16_t*)ws;                     // 128*1024*2  = 262144 B
    bf16_t* h   = (bf16_t*)(ws + 262144);          // 128*512*2   = 131072 B
    bf16_t* vT  = (bf16_t*)(ws + 393216);          // 40000*128*2 = 10240000 B

    k_bn    <<<64,  256, 0, stream>>>(x, gamma, beta, xn);
    k_gemm1 <<<256, 64,  0, stream>>>(xn, W1, b1, h);
    k_gemm_v<<<625, 256, 0, stream>>>(h, Wslm, bslm, vT);
    k_gemm_y<<<782, 256, 0, stream>>>(h, W2, b2, vT, slw, slidx, out);
}

// Round 4
// 330.866 us; speedup vs baseline: 1.0052x; 1.0052x over previous
//
#include <hip/hip_runtime.h>

#define LL 64
#define DD 1024
#define HH 512
#define SS 50000
#define VV 40000
#define KD 32
#define MM 128  // B*L

// packed-weight geometry: pair = 128 cols, step = 32 k, chunk = 8 bf16 (16 B)
#define NPAIR_W1 4      // 512 cols
#define NPAIR_V  313    // 40064 cols (padded)
#define NPAIR_Y  391    // 50048 cols (padded)

typedef __bf16 bf16_t;
typedef __bf16 bf16x8 __attribute__((ext_vector_type(8)));
typedef __bf16 bf16x4 __attribute__((ext_vector_type(4)));
typedef __bf16 bf16x2 __attribute__((ext_vector_type(2)));
typedef float f32x4 __attribute__((ext_vector_type(4)));

__device__ __forceinline__ void async_ld16(const void* g, void* l) {
    __builtin_amdgcn_global_load_lds(
        (const __attribute__((address_space(1))) void*)g,
        (__attribute__((address_space(3))) void*)l, 16, 0, 0);
}

#define WAITV(N) asm volatile("s_waitcnt vmcnt(" #N ")" ::: "memory")

// ---------------- BatchNorm body (used by k_prep blocks 0..63)
__device__ __forceinline__ void bn_body(int l, const float* __restrict__ x,
        const float* __restrict__ gamma, const float* __restrict__ beta,
        bf16_t* __restrict__ xn) {
    int t = threadIdx.x;
    int b = t >> 7;
    int d0 = (t & 127) << 3;
    const float* xp = x + (size_t)(b * LL + l) * DD + d0;
    float4 v0 = *(const float4*)xp;
    float4 v1 = *(const float4*)(xp + 4);
    float s  = v0.x + v0.y + v0.z + v0.w + v1.x + v1.y + v1.z + v1.w;
    float ss = v0.x*v0.x + v0.y*v0.y + v0.z*v0.z + v0.w*v0.w
             + v1.x*v1.x + v1.y*v1.y + v1.z*v1.z + v1.w*v1.w;
    #pragma unroll
    for (int off = 32; off > 0; off >>= 1) {
        s  += __shfl_xor(s, off);
        ss += __shfl_xor(ss, off);
    }
    __shared__ float red[8];
    int wv = t >> 6, ln = t & 63;
    if (ln == 0) { red[wv] = s; red[4 + wv] = ss; }
    __syncthreads();
    float tot  = red[0] + red[1] + red[2] + red[3];
    float tots = red[4] + red[5] + red[6] + red[7];
    float mean = tot * (1.0f / 2048.0f);
    float var  = tots * (1.0f / 2048.0f) - mean * mean;
    float rstd = rsqrtf(var + 1e-5f);
    float g   = gamma[l] * rstd;
    float ofs = beta[l] - mean * g;
    bf16x8 o;
    o[0] = (bf16_t)(v0.x * g + ofs);
    o[1] = (bf16_t)(v0.y * g + ofs);
    o[2] = (bf16_t)(v0.z * g + ofs);
    o[3] = (bf16_t)(v0.w * g + ofs);
    o[4] = (bf16_t)(v1.x * g + ofs);
    o[5] = (bf16_t)(v1.y * g + ofs);
    o[6] = (bf16_t)(v1.z * g + ofs);
    o[7] = (bf16_t)(v1.w * g + ofs);
    *(bf16x8*)(xn + (size_t)(b * LL + l) * DD + d0) = o;
}

// ---------------- conv body: pack one (pair, step) unit of W fp32 -> chunked bf16
// chunk cid (0..511): ns=cid>>8, wv=(cid>>6)&3, q=(cid>>4)&3, c=cid&15
//   col = pair*128 + ns*64 + wv*16 + c ; holds W[step*32+q*8 .. +8][col]
__device__ __forceinline__ void conv_body(const float* __restrict__ src,
        bf16_t* __restrict__ dst, int p, int s, int scols, int kst) {
    int t = threadIdx.x;
    #pragma unroll
    for (int half = 0; half < 2; ++half) {
        int cid = t + half * 256;
        int c = cid & 15, qq = (cid >> 4) & 3, wvv = (cid >> 6) & 3, ns = cid >> 8;
        int col = p * 128 + ns * 64 + wvv * 16 + c;
        int k0 = s * 32 + qq * 8;
        bf16x8 o = {};
        if (col < scols) {
            #pragma unroll
            for (int i = 0; i < 8; ++i)
                o[i] = (bf16_t)src[(size_t)(k0 + i) * scols + col];
        }
        *(bf16x8*)(dst + ((size_t)(p * kst + s) * 512 + cid) * 8) = o;
    }
}

// ---------------- Kernel 1: bn (64 blocks) + conv W1 (128 units)
__global__ __launch_bounds__(256) void k_prep(const float* __restrict__ x,
        const float* __restrict__ gamma, const float* __restrict__ beta,
        bf16_t* __restrict__ xn, const float* __restrict__ W1,
        bf16_t* __restrict__ W1p) {
    int bid = blockIdx.x;
    if (bid < 64) { bn_body(bid, x, gamma, beta, xn); return; }
    int u = bid - 64;                 // 0..127: W1 pack, p=u>>5, s=u&31
    conv_body(W1, W1p, u >> 5, u & 31, HH, 32);
}

// ---------------- shared pipelined GEMM core: BN=128, 2-buffer, vmcnt(4) counted
// LDS per buf: [0..8191] = W pair chunks (512), [8192..16383] = A chunks (512)
template<int KSTEPS>
__device__ __forceinline__ void gemm_pipe(const bf16_t* __restrict__ A, int lda,
        const bf16_t* __restrict__ Wp, int pair, char (*smem)[16384],
        f32x4 (*acc)[2]) {
    int t = threadIdx.x;
    int row0 = ((t >> 6) << 4) + (t & 15);
    int koff = ((t >> 4) & 3) * 8;
    const bf16_t* a0 = A + (size_t)row0 * lda + koff;
    const bf16_t* a1 = A + (size_t)(row0 + 64) * lda + koff;
    const bf16_t* w0 = Wp + (size_t)pair * KSTEPS * 4096 + t * 8;

    #define STAGE_P(buf, st) do { \
        async_ld16(w0 + (size_t)(st) * 4096, smem[buf] + t * 16); \
        async_ld16(w0 + (size_t)(st) * 4096 + 2048, smem[buf] + (t + 256) * 16); \
        async_ld16(a0 + (st) * 32, smem[buf] + 8192 + t * 16); \
        async_ld16(a1 + (st) * 32, smem[buf] + 8192 + (t + 256) * 16); } while (0)

    STAGE_P(0, 0); STAGE_P(1, 1);      // 8 loads/thread in flight
    int lane = t & 63, wv = t >> 6;

    auto comp = [&](int cur) {
        const bf16_t* wl = (const bf16_t*)smem[cur];
        const bf16_t* al = (const bf16_t*)(smem[cur] + 8192);
        bf16x8 b0 = *(const bf16x8*)(wl + (size_t)(wv * 64 + lane) * 8);
        bf16x8 b1 = *(const bf16x8*)(wl + (size_t)(256 + wv * 64 + lane) * 8);
        #pragma unroll
        for (int ms = 0; ms < 8; ++ms) {
            bf16x8 afr = *(const bf16x8*)(al + (size_t)(ms * 64 + lane) * 8);
            acc[ms][0] = __builtin_amdgcn_mfma_f32_16x16x32_bf16(afr, b0, acc[ms][0], 0, 0, 0);
            acc[ms][1] = __builtin_amdgcn_mfma_f32_16x16x32_bf16(afr, b1, acc[ms][1], 0, 0, 0);
        }
    };

    #pragma unroll 1
    for (int st = 0; st < KSTEPS - 2; ++st) {
        WAITV(4);                      // own stage[st] (oldest 4) landed
        __builtin_amdgcn_s_barrier();  // -> buffer complete across waves
        comp(st & 1);
        __builtin_amdgcn_s_barrier();  // all done reading before overwrite
        STAGE_P(st & 1, st + 2);
    }
    WAITV(4); __builtin_amdgcn_s_barrier(); comp(0);   // step KSTEPS-2 (even)
    WAITV(0); __builtin_amdgcn_s_barrier(); comp(1);   // step KSTEPS-1
    #undef STAGE_P
}

// ---------------- Kernel 2: gemm1 (4 blocks) + conv Wslm (5008 units)
__global__ __launch_bounds__(256) void k_gemm1p(const bf16_t* __restrict__ xn,
        const bf16_t* __restrict__ W1p, const float* __restrict__ b1,
        bf16_t* __restrict__ h, const float* __restrict__ Wslm,
        bf16_t* __restrict__ Wvp) {
    __shared__ __align__(16) char smem[2][16384];
    int bid = blockIdx.x;
    if (bid >= NPAIR_W1) {
        int u = bid - NPAIR_W1;
        conv_body(Wslm, Wvp, u >> 4, u & 15, VV, 16);
        return;
    }
    f32x4 acc[8][2] = {};
    gemm_pipe<32>(xn, DD, W1p, bid, smem, acc);
    int t = threadIdx.x, lane = t & 63, wv = t >> 6;
    int c = lane & 15, q = lane >> 4;
    #pragma unroll
    for (int ns = 0; ns < 2; ++ns) {
        int col = bid * 128 + ns * 64 + wv * 16 + c;
        float bias = b1[col];
        #pragma unroll
        for (int ms = 0; ms < 8; ++ms) {
            #pragma unroll
            for (int rr = 0; rr < 4; ++rr) {
                int m = ms * 16 + q * 4 + rr;
                float v = acc[ms][ns][rr] + bias;
                h[(size_t)m * HH + col] = (bf16_t)(v > 0.f ? v : 0.f);
            }
        }
    }
}

// ---------------- Kernel 3: gemm_v (313 blocks) + conv W2 (6256 units)
__global__ __launch_bounds__(256) void k_gemm_vp(const bf16_t* __restrict__ h,
        const bf16_t* __restrict__ Wvp, const float* __restrict__ bslm,
        bf16_t* __restrict__ vT, const float* __restrict__ W2,
        bf16_t* __restrict__ W2p) {
    __shared__ __align__(16) char smem[2][16384];
    int bid = blockIdx.x;
    if (bid >= NPAIR_V) {
        int u = bid - NPAIR_V;
        conv_body(W2, W2p, u >> 4, u & 15, SS, 16);
        return;
    }
    f32x4 acc[8][2] = {};
    gemm_pipe<16>(h, HH, Wvp, bid, smem, acc);
    int t = threadIdx.x, lane = t & 63, wv = t >> 6;
    int c = lane & 15, q = lane >> 4;
    #pragma unroll
    for (int ns = 0; ns < 2; ++ns) {
        int col = bid * 128 + ns * 64 + wv * 16 + c;
        if (col < VV) {
            float bias = bslm[col];
            #pragma unroll
            for (int ms = 0; ms < 8; ++ms) {
                bf16x4 o;
                #pragma unroll
                for (int rr = 0; rr < 4; ++rr) o[rr] = (bf16_t)(acc[ms][ns][rr] + bias);
                *(bf16x4*)(vT + (size_t)col * MM + ms * 16 + q * 4) = o;
            }
        }
    }
}

// ---------------- Kernel 4: gather — one wave per s, lane owns 2 m-values.
__global__ __launch_bounds__(256) void k_gather(const bf16_t* __restrict__ vT,
        const float* __restrict__ slw, const int* __restrict__ slidx,
        bf16_t* __restrict__ slm) {
    int t = threadIdx.x;
    int wv = t >> 6, lane = t & 63;
    int s = blockIdx.x * 4 + wv;        // 50000 = 12500*4, exact
    int idv = slidx[(size_t)s * KD + (lane & 31)];
    float wgt = slw[(size_t)s * KD + (lane & 31)];
    unsigned int u[KD];
    #pragma unroll
    for (int k = 0; k < KD; ++k) {
        int id = __shfl(idv, k);
        u[k] = *(const unsigned int*)(vT + (size_t)id * MM + lane * 2);
    }
    float a0 = 0.f, a1 = 0.f;
    #pragma unroll
    for (int k = 0; k < KD; ++k) {
        float w = __shfl(wgt, k);
        a0 += w * __uint_as_float(u[k] << 16);
        a1 += w * __uint_as_float(u[k] & 0xffff0000u);
    }
    bf16x2 o;
    o[0] = (bf16_t)a0;
    o[1] = (bf16_t)a1;
    *(bf16x2*)(slm + (size_t)s * MM + lane * 2) = o;
}

// ---------------- Kernel 5: out = h @ W2 + b2 + 0.1 * slm^T   (packed W2)
__global__ __launch_bounds__(256) void k_gemm_yp(const bf16_t* __restrict__ h,
        const bf16_t* __restrict__ W2p, const float* __restrict__ b2,
        const bf16_t* __restrict__ slm, float* __restrict__ out) {
    __shared__ __align__(16) char smem[2][16384];
    int bid = blockIdx.x;
    f32x4 acc[8][2] = {};
    gemm_pipe<16>(h, HH, W2p, bid, smem, acc);
    int t = threadIdx.x, lane = t & 63, wv = t >> 6;
    int c = lane & 15, q = lane >> 4;
    #pragma unroll
    for (int ns = 0; ns < 2; ++ns) {
        int col = bid * 128 + ns * 64 + wv * 16 + c;
        if (col < SS) {
            float bias = b2[col];
            #pragma unroll
            for (int ms = 0; ms < 8; ++ms) {
                bf16x4 sv = *(const bf16x4*)(slm + (size_t)col * MM + ms * 16 + q * 4);
                #pragma unroll
                for (int rr = 0; rr < 4; ++rr) {
                    int m = ms * 16 + q * 4 + rr;
                    out[(size_t)m * SS + col] = acc[ms][ns][rr] + bias + 0.1f * (float)sv[rr];
                }
            }
        }
    }
}

extern "C" void kernel_launch(void* const* d_in, const int* in_sizes, int n_in,
                              void* d_out, int out_size, void* d_ws, size_t ws_size,
                              hipStream_t stream) {
    const float* x     = (const float*)d_in[0];
    const float* gamma = (const float*)d_in[1];
    const float* beta  = (const float*)d_in[2];
    const float* W1    = (const float*)d_in[3];
    const float* b1    = (const float*)d_in[4];
    const float* W2    = (const float*)d_in[5];
    const float* b2    = (const float*)d_in[6];
    const float* Wslm  = (const float*)d_in[7];
    const float* bslm  = (const float*)d_in[8];
    const float* slw   = (const float*)d_in[9];
    const int*   slidx = (const int*)d_in[10];
    float* out = (float*)d_out;

    char* ws = (char*)d_ws;
    bf16_t* xn  = (bf16_t*)ws;                      // 262,144 B
    bf16_t* h   = (bf16_t*)(ws + 262144);           // 131,072 B
    bf16_t* vT  = (bf16_t*)(ws + 393216);           // 10,240,000 B
    bf16_t* slm = (bf16_t*)(ws + 10633216);         // 12,800,000 B
    bf16_t* W1p = (bf16_t*)(ws + 23433216);         // 1,048,576 B
    bf16_t* Wvp = (bf16_t*)(ws + 24481792);         // 41,025,536 B
    bf16_t* W2p = (bf16_t*)(ws + 65507328);         // 51,249,152 B  (end ~116.8 MB)

    k_prep   <<<64 + 128,          256, 0, stream>>>(x, gamma, beta, xn, W1, W1p);
    k_gemm1p <<<NPAIR_W1 + 5008,   256, 0, stream>>>(xn, W1p, b1, h, Wslm, Wvp);
    k_gemm_vp<<<NPAIR_V + 6256,    256, 0, stream>>>(h, Wvp, bslm, vT, W2, W2p);
    k_gather <<<12500,             256, 0, stream>>>(vT, slw, slidx, slm);
    k_gemm_yp<<<NPAIR_Y,           256, 0, stream>>>(h, W2p, b2, slm, out);
}